// Round 1
// baseline (57.875 us; speedup 1.0000x reference)
//
#include <hip/hip_runtime.h>

// Upsample 2x2x2 with binomial blur [1,4,6,4,1]/8 per axis, edge padding.
// Derived closed form (per axis, clamp c() to [0,47]):
//   y[2a]   = (x[c(a-1)] + 6*x[a] + x[c(a+1)]) / 8
//   y[2a+1] = (x[a] + x[c(a+1)]) / 2
// Fully separable; each thread computes a 2x2x4 output block (one input-w pair).

constexpr int DIN = 48, HIN = 48, WIN = 48;
constexpr int DOUT = 96, HOUT = 96, WOUT = 96;
constexpr int NC = 2 * 32;
constexpr int TPW = WIN / 2;  // 24 w-pairs per input row
constexpr int TOTAL = NC * DIN * HIN * TPW;  // 3,538,944 threads

__global__ __launch_bounds__(256) void Upsample2x2x2_kernel(
    const float* __restrict__ x, float* __restrict__ out)
{
    int idx = blockIdx.x * 256 + threadIdx.x;
    if (idx >= TOTAL) return;

    int t    = idx % TPW;
    int rest = idx / TPW;
    int b    = rest % HIN;
    rest    /= HIN;
    int a    = rest % DIN;
    int nc   = rest / DIN;

    const float* __restrict__ xb = x + (size_t)nc * (DIN * HIN * WIN);

    const int ai[3] = { max(a - 1, 0), a, min(a + 1, DIN - 1) };
    const int bi[3] = { max(b - 1, 0), b, min(b + 1, HIN - 1) };
    const int c0 = 2 * t;
    const int cm = max(c0 - 1, 0);
    const int cp = min(c0 + 2, WIN - 1);

    // W-stage: for each (d,h) neighbor row, produce 4 w-combined values
    // [even(c0), odd(c0), even(c0+1), odd(c0+1)]
    float r[3][3][4];
    #pragma unroll
    for (int i = 0; i < 3; i++) {
        #pragma unroll
        for (int j = 0; j < 3; j++) {
            const float* __restrict__ row = xb + ((size_t)ai[i] * HIN + bi[j]) * WIN;
            float v0 = row[cm];
            float v1 = row[c0];
            float v2 = row[c0 + 1];
            float v3 = row[cp];
            r[i][j][0] = (v0 + 6.0f * v1 + v2) * 0.125f;
            r[i][j][1] = (v1 + v2) * 0.5f;
            r[i][j][2] = (v1 + 6.0f * v2 + v3) * 0.125f;
            r[i][j][3] = (v2 + v3) * 0.5f;
        }
    }

    // H-stage
    float he[3][4], ho[3][4];
    #pragma unroll
    for (int i = 0; i < 3; i++) {
        #pragma unroll
        for (int k = 0; k < 4; k++) {
            he[i][k] = (r[i][0][k] + 6.0f * r[i][1][k] + r[i][2][k]) * 0.125f;
            ho[i][k] = (r[i][1][k] + r[i][2][k]) * 0.5f;
        }
    }

    // D-stage: 4 output rows of 4 w-values
    float o00[4], o01[4], o10[4], o11[4];  // (2a,2b) (2a,2b+1) (2a+1,2b) (2a+1,2b+1)
    #pragma unroll
    for (int k = 0; k < 4; k++) {
        o00[k] = (he[0][k] + 6.0f * he[1][k] + he[2][k]) * 0.125f;
        o01[k] = (ho[0][k] + 6.0f * ho[1][k] + ho[2][k]) * 0.125f;
        o10[k] = (he[1][k] + he[2][k]) * 0.5f;
        o11[k] = (ho[1][k] + ho[2][k]) * 0.5f;
    }

    float* __restrict__ ob = out + (size_t)nc * (DOUT * HOUT * WOUT);
    size_t base = ((size_t)(2 * a) * HOUT + 2 * b) * WOUT + 4 * t;

    *reinterpret_cast<float4*>(ob + base) =
        make_float4(o00[0], o00[1], o00[2], o00[3]);
    *reinterpret_cast<float4*>(ob + base + WOUT) =
        make_float4(o01[0], o01[1], o01[2], o01[3]);
    *reinterpret_cast<float4*>(ob + base + (size_t)HOUT * WOUT) =
        make_float4(o10[0], o10[1], o10[2], o10[3]);
    *reinterpret_cast<float4*>(ob + base + (size_t)HOUT * WOUT + WOUT) =
        make_float4(o11[0], o11[1], o11[2], o11[3]);
}

extern "C" void kernel_launch(void* const* d_in, const int* in_sizes, int n_in,
                              void* d_out, int out_size, void* d_ws, size_t ws_size,
                              hipStream_t stream) {
    const float* x = (const float*)d_in[0];
    // d_in[1] = blur kernel (constant by construction; weights folded in),
    // d_in[2] = output_shape (fixed 2,32,96,96,96) — both unused.
    float* out = (float*)d_out;
    int blocks = (TOTAL + 255) / 256;  // 13824, exact
    Upsample2x2x2_kernel<<<blocks, 256, 0, stream>>>(x, out);
}

// Round 3
// 47.787 us; speedup vs baseline: 1.2111x; 1.2111x over previous
//
#include <hip/hip_runtime.h>

// 2x upsample with binomial blur [1,4,6,4,1]/8 per axis, edge clamp.
// Per-axis closed form (clamp c() to [0,47]):
//   y[2a]   = (x[c(a-1)] + 6*x[a] + x[c(a+1)]) / 8
//   y[2a+1] = (x[a] + x[c(a+1)]) / 2
// Each thread: 2x2x2-input block -> 4x4x4 output block (64 floats).
// All /8 and /2 scaling deferred to one final multiply per output
// (exact powers of two -> bitwise identical to staged scaling).

typedef float f32x4 __attribute__((ext_vector_type(4)));

constexpr int DIN = 48, HIN = 48, WIN = 48;
constexpr int HW = HIN * WIN;          // 2304
constexpr int DOUT = 96, HOUT = 96, WOUT = 96;
constexpr int NC = 64;
constexpr int THREADS = NC * 24 * 24 * 24;  // 884736

__global__ __launch_bounds__(256) void Upsample2x2x2_kernel(
    const float* __restrict__ x, float* __restrict__ out)
{
    int idx = blockIdx.x * 256 + threadIdx.x;
    int t   = idx % 24;        // w-pair group: input w0 = 2t, outputs w 4t..4t+3
    int tmp = idx / 24;
    int b0h = tmp % 24;
    tmp    /= 24;
    int a0h = tmp % 24;
    int nc  = tmp / 24;

    const int a0 = a0h * 2, b0 = b0h * 2, w0 = t * 2;
    const float* __restrict__ xb = x + (size_t)nc * (DIN * HW);

    const int ai[4] = { a0 > 0 ? a0 - 1 : 0, a0, a0 + 1,
                        a0 + 2 < DIN ? a0 + 2 : DIN - 1 };
    const int bi[4] = { b0 > 0 ? b0 - 1 : 0, b0, b0 + 1,
                        b0 + 2 < HIN ? b0 + 2 : HIN - 1 };
    const int wm = w0 > 0 ? w0 - 1 : 0;
    const int wp = w0 + 2 < WIN ? w0 + 2 : WIN - 1;

    // W-stage (unscaled): per neighbor row, 4 values
    // k0 = E(w0) = u0+6u1+u2 ; k1 = O(w0) = u1+u2
    // k2 = E(w0+1) = u1+6u2+u3 ; k3 = O(w0+1) = u2+u3
    float r[4][4][4];
    #pragma unroll
    for (int i = 0; i < 4; i++) {
        const float* __restrict__ xd = xb + ai[i] * HW;
        #pragma unroll
        for (int j = 0; j < 4; j++) {
            const float* __restrict__ row = xd + bi[j] * WIN;
            float2 m = *reinterpret_cast<const float2*>(row + w0);  // 8B aligned
            float u0 = row[wm];
            float u3 = row[wp];
            float u1 = m.x, u2 = m.y;
            r[i][j][0] = fmaf(6.f, u1, u0) + u2;
            r[i][j][1] = u1 + u2;
            r[i][j][2] = fmaf(6.f, u2, u1) + u3;
            r[i][j][3] = u2 + u3;
        }
    }

    float* __restrict__ ob = out + (size_t)nc * (DOUT * HOUT * WOUT);
    const size_t obase = ((size_t)(a0 * 2) * HOUT + (b0 * 2)) * WOUT + t * 4;

    #pragma unroll
    for (int win = 0; win < 2; win++) {   // h output pair 2(b0+win), +1
        float He[4][4], Ho[4][4];         // H-combined, per d-row, unscaled
        #pragma unroll
        for (int i = 0; i < 4; i++)
            #pragma unroll
            for (int k = 0; k < 4; k++) {
                He[i][k] = fmaf(6.f, r[i][win + 1][k], r[i][win][k]) + r[i][win + 2][k];
                Ho[i][k] = r[i][win + 1][k] + r[i][win + 2][k];
            }

        #pragma unroll
        for (int ap = 0; ap < 2; ap++) {  // d output pair 2(a0+ap), +1
            float vee[4], voe[4], veo[4], voo[4];
            #pragma unroll
            for (int k = 0; k < 4; k++) {
                vee[k] = fmaf(6.f, He[ap + 1][k], He[ap][k]) + He[ap + 2][k];
                voe[k] = He[ap + 1][k] + He[ap + 2][k];
                veo[k] = fmaf(6.f, Ho[ap + 1][k], Ho[ap][k]) + Ho[ap + 2][k];
                voo[k] = Ho[ap + 1][k] + Ho[ap + 2][k];
            }
            size_t rbase = obase + ((size_t)(ap * 2) * HOUT + win * 2) * WOUT;
            // scales: per-axis even=1/8, odd=1/2; w-parity alternates within f32x4
            f32x4 s0 = { vee[0] * (1.f/512), vee[1] * (1.f/128),
                         vee[2] * (1.f/512), vee[3] * (1.f/128) };
            f32x4 s1 = { veo[0] * (1.f/128), veo[1] * (1.f/32),
                         veo[2] * (1.f/128), veo[3] * (1.f/32) };
            f32x4 s2 = { voe[0] * (1.f/128), voe[1] * (1.f/32),
                         voe[2] * (1.f/128), voe[3] * (1.f/32) };
            f32x4 s3 = { voo[0] * (1.f/32),  voo[1] * (1.f/8),
                         voo[2] * (1.f/32),  voo[3] * (1.f/8) };
            __builtin_nontemporal_store(s0, reinterpret_cast<f32x4*>(ob + rbase));
            __builtin_nontemporal_store(s1, reinterpret_cast<f32x4*>(ob + rbase + WOUT));
            __builtin_nontemporal_store(s2, reinterpret_cast<f32x4*>(ob + rbase + (size_t)HOUT * WOUT));
            __builtin_nontemporal_store(s3, reinterpret_cast<f32x4*>(ob + rbase + (size_t)HOUT * WOUT + WOUT));
        }
    }
}

extern "C" void kernel_launch(void* const* d_in, const int* in_sizes, int n_in,
                              void* d_out, int out_size, void* d_ws, size_t ws_size,
                              hipStream_t stream) {
    const float* x = (const float*)d_in[0];
    float* out = (float*)d_out;
    int blocks = THREADS / 256;  // 3456, exact
    Upsample2x2x2_kernel<<<blocks, 256, 0, stream>>>(x, out);
}